// Round 4
// baseline (271.271 us; speedup 1.0000x reference)
//
#include <hip/hip_runtime.h>
#include <math.h>

#define NCOL 32
#define DDIM 512
#define NPAIR 16
#define CATS 10
#define ROWS 16                    /* rows per wave */
#define ROW_STRIDE (NCOL * DDIM)   /* 16384 floats between consecutive b rows */

// v += dpp_permuted(v). old=0 / bound_ctrl=false: masked-off rows contribute 0.
template <int CTRL, int ROW_MASK>
__device__ __forceinline__ float dpp_add(float v) {
    int t = __builtin_amdgcn_update_dpp(0, __float_as_int(v), CTRL, ROW_MASK, 0xf, false);
    return v + __int_as_float(t);
}
// pure DPP move: returns permuted value (0 in masked-off rows).
template <int CTRL, int ROW_MASK>
__device__ __forceinline__ float dpp_mov(float v) {
    int t = __builtin_amdgcn_update_dpp(0, __float_as_int(v), CTRL, ROW_MASK, 0xf, false);
    return __int_as_float(t);
}

// After this: lane31 = sum(lanes 0..31), lane63 = sum(lanes 32..63). VALU only.
__device__ __forceinline__ float wave_reduce_halves(float v) {
    v = dpp_add<0x111, 0xf>(v);  // row_shr:1
    v = dpp_add<0x112, 0xf>(v);  // row_shr:2
    v = dpp_add<0x114, 0xf>(v);  // row_shr:4
    v = dpp_add<0x118, 0xf>(v);  // row_shr:8  -> lane15 of each row16 = row sum
    v = dpp_add<0x142, 0xa>(v);  // row_bcast:15 -> lane31, lane63 hold half-sums
    return v;
}
// Full 64-lane sum, valid in lane 63.
__device__ __forceinline__ float wave_reduce_full(float v) {
    v = wave_reduce_halves(v);
    v = dpp_add<0x143, 0xc>(v);  // row_bcast:31 into rows 2,3 -> lane63 = total
    return v;
}

// Load one pair-row: even col (E) and odd col (O), 4 KiB contiguous per wave.
#define LOADPAIR(Ea, Eb, Oa, Ob, r) do {                          \
    const float* _p = xb + (size_t)(r) * ROW_STRIDE;              \
    Ea = *(const float4*)(_p + lane * 4);                         \
    Eb = *(const float4*)(_p + 256 + lane * 4);                   \
    Oa = *(const float4*)(_p + DDIM + lane * 4);                  \
    Ob = *(const float4*)(_p + DDIM + 256 + lane * 4);            \
} while (0)

// Process one pair-row: numeric (identical math to R2's NUM_ROW) + categorical
// (identical math to R2's CAT_ROW), fused 8-byte store from lane 63.
#define PROCPAIR(Ea, Eb, Oa, Ob, idx) do {                        \
    /* ---- categorical on odd col ---- */                        \
    double best = -1.0e300;                                       \
    int bi = 0;                                                   \
    _Pragma("unroll")                                             \
    for (int c = 0; c < CATS; ++c) {                              \
        float s = Oa.x * wc[c];                                   \
        s = fmaf(Oa.y, wc[10 + c], s);                            \
        s = fmaf(Oa.z, wc[20 + c], s);                            \
        s = fmaf(Oa.w, wc[30 + c], s);                            \
        s = fmaf(Ob.x, wc[40 + c], s);                            \
        s = fmaf(Ob.y, wc[50 + c], s);                            \
        s = fmaf(Ob.z, wc[60 + c], s);                            \
        s = fmaf(Ob.w, wc[70 + c], s);                            \
        s = wave_reduce_halves(s);                                \
        float slo = dpp_mov<0x143, 0xc>(s);                       \
        double d = (double)s + (double)slo + biasd[c];            \
        if (d > best) { best = d; bi = c; }                       \
    }                                                             \
    /* ---- numeric on even col ---- */                           \
    float sn = Ea.x * w[0];                                       \
    sn = fmaf(Ea.y, w[1], sn);                                    \
    sn = fmaf(Ea.z, w[2], sn);                                    \
    sn = fmaf(Ea.w, w[3], sn);                                    \
    sn = fmaf(Eb.x, w[4], sn);                                    \
    sn = fmaf(Eb.y, w[5], sn);                                    \
    sn = fmaf(Eb.z, w[6], sn);                                    \
    sn = fmaf(Eb.w, w[7], sn);                                    \
    sn = wave_reduce_full(sn);                                    \
    if (lane == 63) {                                             \
        float2 o2 = make_float2(tanhf(sn + bias), (float)bi);     \
        *(float2*)(ob + (size_t)(idx) * NCOL) = o2;               \
    }                                                             \
} while (0)

__global__ __launch_bounds__(256, 3) void pair_kernel(
    const float* __restrict__ x,
    const float* __restrict__ Wn,
    const float* __restrict__ bn,
    const float* __restrict__ Wc,
    const float* __restrict__ bc,
    float* __restrict__ out)
{
    const int lane  = threadIdx.x & 63;
    const int wslot = threadIdx.x >> 6;
    const int wid   = __builtin_amdgcn_readfirstlane(blockIdx.x * 4 + wslot); // 0..8191
    const int p     = wid & (NPAIR - 1);
    const int chunk = wid >> 4;                 // 0..511
    const size_t b0 = (size_t)chunk * ROWS;

    // numeric weights (per-lane slice of Wn[p])
    float w[8];
    {
        float4 wa = *(const float4*)(Wn + p * DDIM + lane * 4);
        float4 wb = *(const float4*)(Wn + p * DDIM + 256 + lane * 4);
        w[0]=wa.x; w[1]=wa.y; w[2]=wa.z; w[3]=wa.w;
        w[4]=wb.x; w[5]=wb.y; w[6]=wb.z; w[7]=wb.w;
    }
    const float bias = __int_as_float(
        __builtin_amdgcn_readfirstlane(__float_as_int(bn[p])));

    // categorical weights: wc[dd*10+c] low half (d=4*lane+dd), wc[40+...] high
    float wc[80];
    {
        const float* w0 = Wc + ((size_t)p * DDIM + lane * 4) * CATS;
        const float* w1 = Wc + ((size_t)p * DDIM + 256 + lane * 4) * CATS;
        #pragma unroll
        for (int k = 0; k < 10; ++k) {
            float4 t = *(const float4*)(w0 + k * 4);
            wc[4*k] = t.x; wc[4*k+1] = t.y; wc[4*k+2] = t.z; wc[4*k+3] = t.w;
        }
        #pragma unroll
        for (int k = 0; k < 10; ++k) {
            float4 t = *(const float4*)(w1 + k * 4);
            wc[40+4*k] = t.x; wc[40+4*k+1] = t.y; wc[40+4*k+2] = t.z; wc[40+4*k+3] = t.w;
        }
    }
    double biasd[CATS];  // wave-uniform -> SGPR pairs
    #pragma unroll
    for (int c = 0; c < CATS; ++c)
        biasd[c] = (double)__int_as_float(
            __builtin_amdgcn_readfirstlane(__float_as_int(bc[p * CATS + c])));

    // wave-uniform base of this pair's even column; odd column is +DDIM.
    const float* xb = x + b0 * ROW_STRIDE + (size_t)(2 * p) * DDIM;
    float* ob = out + b0 * NCOL + 2 * p;

    // depth-2 rotating named pair-buffers (8 float4 = 32 VGPR)
    float4 AEa, AEb, AOa, AOb, BEa, BEb, BOa, BOb;
    LOADPAIR(AEa, AEb, AOa, AOb, 0);
    LOADPAIR(BEa, BEb, BOa, BOb, 1);
    for (int i = 0; i < ROWS - 2; i += 2) {
        PROCPAIR(AEa, AEb, AOa, AOb, i);
        LOADPAIR(AEa, AEb, AOa, AOb, i + 2);
        PROCPAIR(BEa, BEb, BOa, BOb, i + 1);
        LOADPAIR(BEa, BEb, BOa, BOb, i + 3);
    }
    PROCPAIR(AEa, AEb, AOa, AOb, ROWS - 2);
    PROCPAIR(BEa, BEb, BOa, BOb, ROWS - 1);
}

extern "C" void kernel_launch(void* const* d_in, const int* in_sizes, int n_in,
                              void* d_out, int out_size, void* d_ws, size_t ws_size,
                              hipStream_t stream) {
    const float* x  = (const float*)d_in[0];
    const float* Wn = (const float*)d_in[1];
    const float* bn = (const float*)d_in[2];
    const float* Wc = (const float*)d_in[3];
    const float* bc = (const float*)d_in[4];
    float* out = (float*)d_out;

    // 8192 waves: one per (pair, 16-row chunk); 4 pairs per block share rows.
    hipLaunchKernelGGL(pair_kernel, dim3(2048), dim3(256), 0, stream,
                       x, Wn, bn, Wc, bc, out);
}

// Round 5
// 233.899 us; speedup vs baseline: 1.1598x; 1.1598x over previous
//
#include <hip/hip_runtime.h>
#include <math.h>

#define NCOL 32
#define DDIM 512
#define NPAIR 16
#define CATS 10
#define ROWS_PER_WAVE 64
#define ROW_STRIDE (NCOL * DDIM) /* 16384 floats between consecutive b rows */

// v += dpp_permuted(v). old=0 / bound_ctrl=false: masked-off rows contribute 0.
template <int CTRL, int ROW_MASK>
__device__ __forceinline__ float dpp_add(float v) {
    int t = __builtin_amdgcn_update_dpp(0, __float_as_int(v), CTRL, ROW_MASK, 0xf, false);
    return v + __int_as_float(t);
}
// pure DPP move: returns permuted value (0 in masked-off rows).
template <int CTRL, int ROW_MASK>
__device__ __forceinline__ float dpp_mov(float v) {
    int t = __builtin_amdgcn_update_dpp(0, __float_as_int(v), CTRL, ROW_MASK, 0xf, false);
    return __int_as_float(t);
}

// After this: lane31 = sum(lanes 0..31), lane63 = sum(lanes 32..63). VALU only.
__device__ __forceinline__ float wave_reduce_halves(float v) {
    v = dpp_add<0x111, 0xf>(v);  // row_shr:1
    v = dpp_add<0x112, 0xf>(v);  // row_shr:2
    v = dpp_add<0x114, 0xf>(v);  // row_shr:4
    v = dpp_add<0x118, 0xf>(v);  // row_shr:8  -> lane15 of each row16 = row sum
    v = dpp_add<0x142, 0xa>(v);  // row_bcast:15 -> lane31, lane63 hold half-sums
    return v;
}
// Full 64-lane sum, valid in lane 63.
__device__ __forceinline__ float wave_reduce_full(float v) {
    v = wave_reduce_halves(v);
    v = dpp_add<0x143, 0xc>(v);  // row_bcast:31 into rows 2,3 -> lane63 = total
    return v;
}

#define LOADROW(Ra, Rb, r) do {                                   \
    const float* _p = xb + (size_t)(r) * ROW_STRIDE;              \
    Ra = *(const float4*)(_p + lane * 4);                         \
    Rb = *(const float4*)(_p + 256 + lane * 4);                   \
} while (0)

#define NUM_ROW(Ra, Rb, idx) do {                                 \
    float s = Ra.x * w[0];                                        \
    s = fmaf(Ra.y, w[1], s);                                      \
    s = fmaf(Ra.z, w[2], s);                                      \
    s = fmaf(Ra.w, w[3], s);                                      \
    s = fmaf(Rb.x, w[4], s);                                      \
    s = fmaf(Rb.y, w[5], s);                                      \
    s = fmaf(Rb.z, w[6], s);                                      \
    s = fmaf(Rb.w, w[7], s);                                      \
    s = wave_reduce_full(s);                                      \
    if (lane == 63) ob[(size_t)(idx) * NCOL] = tanhf(s + bias);   \
} while (0)

#define CAT_ROW(Ra, Rb, idx) do {                                 \
    double best = -1.0e300;                                       \
    int bi = 0;                                                   \
    _Pragma("unroll")                                             \
    for (int c = 0; c < CATS; ++c) {                              \
        float s = Ra.x * wc[c];                                   \
        s = fmaf(Ra.y, wc[10 + c], s);                            \
        s = fmaf(Ra.z, wc[20 + c], s);                            \
        s = fmaf(Ra.w, wc[30 + c], s);                            \
        s = fmaf(Rb.x, wc[40 + c], s);                            \
        s = fmaf(Rb.y, wc[50 + c], s);                            \
        s = fmaf(Rb.z, wc[60 + c], s);                            \
        s = fmaf(Rb.w, wc[70 + c], s);                            \
        s = wave_reduce_halves(s);                                \
        float slo = dpp_mov<0x143, 0xc>(s);                       \
        double d = (double)s + (double)slo + (double)biasf[c];    \
        if (d > best) { best = d; bi = c; }                       \
    }                                                             \
    if (lane == 63) ob[(size_t)(idx) * NCOL] = (float)bi;         \
} while (0)

__global__ __launch_bounds__(256, 4) void fused_cols_kernel(
    const float* __restrict__ x,
    const float* __restrict__ Wn,
    const float* __restrict__ bn,
    const float* __restrict__ Wc,
    const float* __restrict__ bc,
    float* __restrict__ out)
{
    const int lane  = threadIdx.x & 63;
    const int wslot = threadIdx.x >> 6;
    const int typ   = blockIdx.x & 1;   // 0 = numeric cols, 1 = categorical cols
    const int tb    = blockIdx.x >> 1;  // 0..511 per type
    const int wid   = __builtin_amdgcn_readfirstlane(tb * 4 + wslot); // 0..2047
    const int p     = wid & (NPAIR - 1);
    const int chunk = wid >> 4;                       // 0..127
    const size_t b0 = (size_t)chunk * ROWS_PER_WAVE;

    if (typ == 0) {
        // ---- numeric: out[b, 2p] = tanh(x[b,2p,:] . Wn[p] + bn[p])
        float w[8];
        {
            float4 wa = *(const float4*)(Wn + p * DDIM + lane * 4);
            float4 wb = *(const float4*)(Wn + p * DDIM + 256 + lane * 4);
            w[0]=wa.x; w[1]=wa.y; w[2]=wa.z; w[3]=wa.w;
            w[4]=wb.x; w[5]=wb.y; w[6]=wb.z; w[7]=wb.w;
        }
        const float bias = __int_as_float(
            __builtin_amdgcn_readfirstlane(__float_as_int(bn[p])));
        const float* xb = x + b0 * ROW_STRIDE + (size_t)(2 * p) * DDIM;
        float* ob = out + b0 * NCOL + 2 * p;

        // depth-4 rotating named buffers (~8 KB in flight per wave)
        float4 R0a,R0b,R1a,R1b,R2a,R2b,R3a,R3b;
        LOADROW(R0a,R0b,0); LOADROW(R1a,R1b,1);
        LOADROW(R2a,R2b,2); LOADROW(R3a,R3b,3);
        for (int i = 0; i < 60; i += 4) {
            NUM_ROW(R0a,R0b,i+0); LOADROW(R0a,R0b,i+4);
            NUM_ROW(R1a,R1b,i+1); LOADROW(R1a,R1b,i+5);
            NUM_ROW(R2a,R2b,i+2); LOADROW(R2a,R2b,i+6);
            NUM_ROW(R3a,R3b,i+3); LOADROW(R3a,R3b,i+7);
        }
        NUM_ROW(R0a,R0b,60); NUM_ROW(R1a,R1b,61);
        NUM_ROW(R2a,R2b,62); NUM_ROW(R3a,R3b,63);
    } else {
        // ---- categorical: out[b, 2p+1] = argmax_c(x[b,2p+1,:] . Wc[p,:,c] + bc[p,c])
        float wc[80];  // wc[dd*10+c] low half (d=4*lane+dd), wc[40+dd*10+c] high half
        {
            const float* w0 = Wc + ((size_t)p * DDIM + lane * 4) * CATS;
            const float* w1 = Wc + ((size_t)p * DDIM + 256 + lane * 4) * CATS;
            #pragma unroll
            for (int k = 0; k < 10; ++k) {
                float4 t = *(const float4*)(w0 + k * 4);
                wc[4*k] = t.x; wc[4*k+1] = t.y; wc[4*k+2] = t.z; wc[4*k+3] = t.w;
            }
            #pragma unroll
            for (int k = 0; k < 10; ++k) {
                float4 t = *(const float4*)(w1 + k * 4);
                wc[40+4*k] = t.x; wc[40+4*k+1] = t.y; wc[40+4*k+2] = t.z; wc[40+4*k+3] = t.w;
            }
        }
        // wave-uniform biases kept as SGPR floats; widened to f64 at use
        // (identical numerics to the f64-array version, -20 VGPR)
        float biasf[CATS];
        #pragma unroll
        for (int c = 0; c < CATS; ++c)
            biasf[c] = __int_as_float(
                __builtin_amdgcn_readfirstlane(__float_as_int(bc[p * CATS + c])));

        const float* xb = x + b0 * ROW_STRIDE + (size_t)(2 * p + 1) * DDIM;
        float* ob = out + b0 * NCOL + 2 * p + 1;

        // depth-2 A/B (as the 128.7 µs version)
        float4 A0 = *(const float4*)(xb + lane * 4);
        float4 A1 = *(const float4*)(xb + 256 + lane * 4);
        float4 B0 = *(const float4*)(xb + ROW_STRIDE + lane * 4);
        float4 B1 = *(const float4*)(xb + ROW_STRIDE + 256 + lane * 4);
        for (int i = 0; i < ROWS_PER_WAVE - 2; i += 2) {
            const float* x2 = xb + (size_t)(i + 2) * ROW_STRIDE;
            const float* x3 = xb + (size_t)(i + 3) * ROW_STRIDE;
            float4 C0 = *(const float4*)(x2 + lane * 4);
            float4 C1 = *(const float4*)(x2 + 256 + lane * 4);
            CAT_ROW(A0, A1, i);
            float4 D0 = *(const float4*)(x3 + lane * 4);
            float4 D1 = *(const float4*)(x3 + 256 + lane * 4);
            CAT_ROW(B0, B1, i + 1);
            A0 = C0; A1 = C1; B0 = D0; B1 = D1;
        }
        CAT_ROW(A0, A1, ROWS_PER_WAVE - 2);
        CAT_ROW(B0, B1, ROWS_PER_WAVE - 1);
    }
}

extern "C" void kernel_launch(void* const* d_in, const int* in_sizes, int n_in,
                              void* d_out, int out_size, void* d_ws, size_t ws_size,
                              hipStream_t stream) {
    const float* x  = (const float*)d_in[0];
    const float* Wn = (const float*)d_in[1];
    const float* bn = (const float*)d_in[2];
    const float* Wc = (const float*)d_in[3];
    const float* bc = (const float*)d_in[4];
    float* out = (float*)d_out;

    // grid 1024 @ 4 blocks/CU resident -> all blocks co-resident, zero tail
    hipLaunchKernelGGL(fused_cols_kernel, dim3(1024), dim3(256), 0, stream,
                       x, Wn, bn, Wc, bc, out);
}

// Round 6
// 118.355 us; speedup vs baseline: 2.2920x; 1.9762x over previous
//
#include <hip/hip_runtime.h>
#include <math.h>

#define NCOL 32
#define DDIM 512
#define NPAIR 16
#define CATS 10
#define ROWS_PER_BLOCK 32
#define ROW_STRIDE (NCOL * DDIM)   /* 16384 floats between consecutive b rows */
#define SLAB_FLOATS 4096           /* 4 pairs x 1024 floats = 16 KiB per row  */

// v += dpp_permuted(v). old=0 / bound_ctrl=false: masked-off rows contribute 0.
template <int CTRL, int ROW_MASK>
__device__ __forceinline__ float dpp_add(float v) {
    int t = __builtin_amdgcn_update_dpp(0, __float_as_int(v), CTRL, ROW_MASK, 0xf, false);
    return v + __int_as_float(t);
}
// pure DPP move: returns permuted value (0 in masked-off rows).
template <int CTRL, int ROW_MASK>
__device__ __forceinline__ float dpp_mov(float v) {
    int t = __builtin_amdgcn_update_dpp(0, __float_as_int(v), CTRL, ROW_MASK, 0xf, false);
    return __int_as_float(t);
}

// After this: lane31 = sum(lanes 0..31), lane63 = sum(lanes 32..63). VALU only.
__device__ __forceinline__ float wave_reduce_halves(float v) {
    v = dpp_add<0x111, 0xf>(v);  // row_shr:1
    v = dpp_add<0x112, 0xf>(v);  // row_shr:2
    v = dpp_add<0x114, 0xf>(v);  // row_shr:4
    v = dpp_add<0x118, 0xf>(v);  // row_shr:8  -> lane15 of each row16 = row sum
    v = dpp_add<0x142, 0xa>(v);  // row_bcast:15 -> lane31, lane63 hold half-sums
    return v;
}
// Full 64-lane sum, valid in lane 63.
__device__ __forceinline__ float wave_reduce_full(float v) {
    v = wave_reduce_halves(v);
    v = dpp_add<0x143, 0xc>(v);  // row_bcast:31 into rows 2,3 -> lane63 = total
    return v;
}

// Block-contiguous streaming: block = 4 consecutive pairs (16 KiB/row slab),
// double-buffered through LDS; math per wave identical to the R2 kernel.
__global__ __launch_bounds__(256, 3) void fused_pairs_lds(
    const float* __restrict__ x,
    const float* __restrict__ Wn,
    const float* __restrict__ bn,
    const float* __restrict__ Wc,
    const float* __restrict__ bc,
    float* __restrict__ out)
{
    __shared__ float buf[2][SLAB_FLOATS];   // 32 KiB
    const int tid   = threadIdx.x;
    const int lane  = tid & 63;
    const int wslot = tid >> 6;
    const int q     = blockIdx.x & 3;        // pair-quad 0..3
    const int chunk = blockIdx.x >> 2;       // 0..255
    const size_t b0 = (size_t)chunk * ROWS_PER_BLOCK;
    const int p     = __builtin_amdgcn_readfirstlane(q * 4 + wslot); // this wave's pair

    // ---- numeric weights (per-lane slice of Wn[p]) — identical to R2
    float w[8];
    {
        float4 wa = *(const float4*)(Wn + p * DDIM + lane * 4);
        float4 wb = *(const float4*)(Wn + p * DDIM + 256 + lane * 4);
        w[0]=wa.x; w[1]=wa.y; w[2]=wa.z; w[3]=wa.w;
        w[4]=wb.x; w[5]=wb.y; w[6]=wb.z; w[7]=wb.w;
    }
    const float bias = __int_as_float(
        __builtin_amdgcn_readfirstlane(__float_as_int(bn[p])));

    // ---- categorical weights: wc[dd*10+c] low half, wc[40+dd*10+c] high half
    float wc[80];
    {
        const float* w0 = Wc + ((size_t)p * DDIM + lane * 4) * CATS;
        const float* w1 = Wc + ((size_t)p * DDIM + 256 + lane * 4) * CATS;
        #pragma unroll
        for (int k = 0; k < 10; ++k) {
            float4 t = *(const float4*)(w0 + k * 4);
            wc[4*k] = t.x; wc[4*k+1] = t.y; wc[4*k+2] = t.z; wc[4*k+3] = t.w;
        }
        #pragma unroll
        for (int k = 0; k < 10; ++k) {
            float4 t = *(const float4*)(w1 + k * 4);
            wc[40+4*k] = t.x; wc[40+4*k+1] = t.y; wc[40+4*k+2] = t.z; wc[40+4*k+3] = t.w;
        }
    }
    double biasd[CATS];  // wave-uniform -> SGPR pairs (as in passing R2)
    #pragma unroll
    for (int c = 0; c < CATS; ++c)
        biasd[c] = (double)__int_as_float(
            __builtin_amdgcn_readfirstlane(__float_as_int(bc[p * CATS + c])));

    // slab base: row b0, columns 8q..8q+7 (pairs 4q..4q+3), 16 KiB contiguous
    const float* xslab = x + b0 * ROW_STRIDE + (size_t)q * SLAB_FLOATS;
    float* ob = out + b0 * NCOL + 2 * p;

    // ---- prologue: stage row 0 into buf[0] (fully coalesced, 16B/thread x4)
    {
        const float* g = xslab;
        #pragma unroll
        for (int it = 0; it < 4; ++it)
            *(float4*)(&buf[0][it * 1024 + tid * 4]) =
                *(const float4*)(g + it * 1024 + tid * 4);
    }
    __syncthreads();

    for (int r = 0; r < ROWS_PER_BLOCK; ++r) {
        const int cur = r & 1;
        const int nxt = cur ^ 1;

        // issue next row's global loads early (latency hides under compute)
        float4 s0, s1, s2, s3;
        const bool have_next = (r + 1 < ROWS_PER_BLOCK);
        if (have_next) {
            const float* g = xslab + (size_t)(r + 1) * ROW_STRIDE;
            s0 = *(const float4*)(g +    0 + tid * 4);
            s1 = *(const float4*)(g + 1024 + tid * 4);
            s2 = *(const float4*)(g + 2048 + tid * 4);
            s3 = *(const float4*)(g + 3072 + tid * 4);
        }

        // this wave's pair from LDS: [E(512) | O(512)] at wslot*1024
        const float* pb = &buf[cur][wslot * 1024];
        float4 Oa = *(const float4*)(pb + 512 + 4 * lane);
        float4 Ob = *(const float4*)(pb + 512 + 256 + 4 * lane);
        float4 Ea = *(const float4*)(pb + 4 * lane);
        float4 Eb = *(const float4*)(pb + 256 + 4 * lane);

        // ---- categorical on odd col (math byte-identical to R2's CAT_ROW)
        double best = -1.0e300;
        int bi = 0;
        #pragma unroll
        for (int c = 0; c < CATS; ++c) {
            float s = Oa.x * wc[c];
            s = fmaf(Oa.y, wc[10 + c], s);
            s = fmaf(Oa.z, wc[20 + c], s);
            s = fmaf(Oa.w, wc[30 + c], s);
            s = fmaf(Ob.x, wc[40 + c], s);
            s = fmaf(Ob.y, wc[50 + c], s);
            s = fmaf(Ob.z, wc[60 + c], s);
            s = fmaf(Ob.w, wc[70 + c], s);
            s = wave_reduce_halves(s);
            float slo = dpp_mov<0x143, 0xc>(s);
            double d = (double)s + (double)slo + biasd[c];
            if (d > best) { best = d; bi = c; }
        }

        // ---- numeric on even col (math byte-identical to R2's NUM_ROW)
        float sn = Ea.x * w[0];
        sn = fmaf(Ea.y, w[1], sn);
        sn = fmaf(Ea.z, w[2], sn);
        sn = fmaf(Ea.w, w[3], sn);
        sn = fmaf(Eb.x, w[4], sn);
        sn = fmaf(Eb.y, w[5], sn);
        sn = fmaf(Eb.z, w[6], sn);
        sn = fmaf(Eb.w, w[7], sn);
        sn = wave_reduce_full(sn);

        if (lane == 63) {
            float2 o2 = make_float2(tanhf(sn + bias), (float)bi);
            *(float2*)(ob + (size_t)r * NCOL) = o2;
        }

        // write next row's slab (buf[nxt] was fully consumed at row r-1)
        if (have_next) {
            *(float4*)(&buf[nxt][   0 + tid * 4]) = s0;
            *(float4*)(&buf[nxt][1024 + tid * 4]) = s1;
            *(float4*)(&buf[nxt][2048 + tid * 4]) = s2;
            *(float4*)(&buf[nxt][3072 + tid * 4]) = s3;
        }
        __syncthreads();
    }
}

extern "C" void kernel_launch(void* const* d_in, const int* in_sizes, int n_in,
                              void* d_out, int out_size, void* d_ws, size_t ws_size,
                              hipStream_t stream) {
    const float* x  = (const float*)d_in[0];
    const float* Wn = (const float*)d_in[1];
    const float* bn = (const float*)d_in[2];
    const float* Wc = (const float*)d_in[3];
    const float* bc = (const float*)d_in[4];
    float* out = (float*)d_out;

    // 1024 blocks: (pair-quad 0..3) x (row-chunk 0..255), 32 rows per block
    hipLaunchKernelGGL(fused_pairs_lds, dim3(1024), dim3(256), 0, stream,
                       x, Wn, bn, Wc, bc, out);
}